// Round 8
// baseline (127.626 us; speedup 1.0000x reference)
//
#include <hip/hip_runtime.h>
#include <stdint.h>
#include <stddef.h>

// MultiHeadAttention: B=2, S=2048, D=1024, H=16, Dh=64
// Round 8:
//   proj3: fused fp32->bf16 QKV GEMMs (reads raw fp32 inputs directly;
//          fp32 LDS staging with XOR-swizzled source; cvt on fragment read).
//          cvt6 pass DELETED. Q pre-scaled; V written transposed [B,H,Dh,S].
//   attn : register-P unnormalized attention (R7) + l computed via MFMA
//          against an all-ones fragment (no per-tile VALU adds / no shuffles).

#define NH  16
#define DH  64
#define SEQ 2048
#define DM  1024
#define NB  2

#define ACT_N (NB * SEQ * DM)   // 4194304
#define W_N   (DM * DM)         // 1048576
#define QSCALE 0.18033688011116012f   // log2(e)/sqrt(64)

typedef float  f32x4  __attribute__((ext_vector_type(4)));
typedef __bf16 bf16x8 __attribute__((ext_vector_type(8)));
typedef __bf16 bf16x4 __attribute__((ext_vector_type(4)));

__device__ __forceinline__ __bf16 f2bf(float f) { return (__bf16)f; }

__device__ __forceinline__ void gload_lds16(const void* g, void* l) {
    __builtin_amdgcn_global_load_lds(
        (const __attribute__((address_space(1))) void*)g,
        (__attribute__((address_space(3))) void*)l, 16, 0, 0);
}

// ---------------------------------------------------------------------------
// proj3: NT GEMM D[m][n] = sum_k X[m][k]*W[n][k] + b[n], fp32 in, bf16 out.
// 128x128 tile, BK=32. fp32 LDS staging [128][32] via global_load_lds with
// XOR-swizzled source chunks (phys chunk p at row r holds logical p^(r&7));
// fragments read as 2x float4 + cvt_pk to bf16x8.
// z==0: Q head-major scaled; z==1: K head-major; z==2: V transposed.
// ---------------------------------------------------------------------------
__global__ __launch_bounds__(256) void proj3(
    const float* __restrict__ X0, const float* __restrict__ X1, const float* __restrict__ X2,
    const float* __restrict__ W0, const float* __restrict__ W1, const float* __restrict__ W2,
    const float* __restrict__ b0, const float* __restrict__ b1, const float* __restrict__ b2,
    __bf16* __restrict__ dq, __bf16* __restrict__ dk, __bf16* __restrict__ dv)
{
    __shared__ __align__(16) char smem[36864];   // 32KB staging / 36KB tbuf (aliased)
    float* sAf = (float*)smem;                    // [128][32] fp32
    float* sBf = (float*)(smem + 16384);          // [128][32] fp32

    const float *X, *W, *bias; __bf16* dst;
    if (blockIdx.z == 0)      { X = X0; W = W0; bias = b0; dst = dq; }
    else if (blockIdx.z == 1) { X = X1; W = W1; bias = b1; dst = dk; }
    else                      { X = X2; W = W2; bias = b2; dst = dv; }

    const int lane = threadIdx.x & 63;
    const int wv   = threadIdx.x >> 6;
    const int mb = blockIdx.x * 128;
    const int nb = blockIdx.y * 128;
    const int lm0 = (wv >> 1) * 64;
    const int ln0 = (wv & 1) * 64;
    const int lr = lane & 15;
    const int lg = lane >> 4;

    // staging: wave wv, iter it covers rows it*32 + wv*8 .. +8 (8 chunks/row).
    // lane l -> row +(l>>3), phys chunk l&7; logical chunk = (l&7) ^ (row&7).
    const int srow = wv * 8 + (lane >> 3);
    const int cst  = (lane & 7) ^ (srow & 7);
    const float* xs = X + (size_t)(mb + srow) * DM + cst * 4;
    const float* ws = W + (size_t)(nb + srow) * DM + cst * 4;
    const int ldst = wv * 256;   // float offset of wave's chunk block (+ it*1024)

    // fragment read offsets: row = lm0/ln0 + t*16 + lr; chunks 2lg, 2lg+1
    const int ca0 = (2 * lg) ^ (lr & 7);
    const int ca1 = (2 * lg + 1) ^ (lr & 7);

    f32x4 acc[4][4];
#pragma unroll
    for (int i = 0; i < 4; ++i)
#pragma unroll
        for (int j = 0; j < 4; ++j) acc[i][j] = (f32x4){0.f, 0.f, 0.f, 0.f};

    for (int k0 = 0; k0 < DM; k0 += 32) {
        __syncthreads();
#pragma unroll
        for (int it = 0; it < 4; ++it) {
            gload_lds16(xs + (size_t)it * 32 * DM + k0, sAf + it * 1024 + ldst);
            gload_lds16(ws + (size_t)it * 32 * DM + k0, sBf + it * 1024 + ldst);
        }
        __syncthreads();

        bf16x8 a[4], b[4];
#pragma unroll
        for (int t = 0; t < 4; ++t) {
            const float* pa = sAf + (lm0 + t * 16 + lr) * 32;
            float4 f0 = *(const float4*)(pa + ca0 * 4);
            float4 f1 = *(const float4*)(pa + ca1 * 4);
            bf16x8 va;
            va[0] = f2bf(f0.x); va[1] = f2bf(f0.y); va[2] = f2bf(f0.z); va[3] = f2bf(f0.w);
            va[4] = f2bf(f1.x); va[5] = f2bf(f1.y); va[6] = f2bf(f1.z); va[7] = f2bf(f1.w);
            a[t] = va;
            const float* pb = sBf + (ln0 + t * 16 + lr) * 32;
            float4 g0 = *(const float4*)(pb + ca0 * 4);
            float4 g1 = *(const float4*)(pb + ca1 * 4);
            bf16x8 vb;
            vb[0] = f2bf(g0.x); vb[1] = f2bf(g0.y); vb[2] = f2bf(g0.z); vb[3] = f2bf(g0.w);
            vb[4] = f2bf(g1.x); vb[5] = f2bf(g1.y); vb[6] = f2bf(g1.z); vb[7] = f2bf(g1.w);
            b[t] = vb;
        }
#pragma unroll
        for (int mt = 0; mt < 4; ++mt)
#pragma unroll
            for (int nt = 0; nt < 4; ++nt)
                acc[mt][nt] = __builtin_amdgcn_mfma_f32_16x16x32_bf16(
                    a[mt], b[nt], acc[mt][nt], 0, 0, 0);
    }

    if (blockIdx.z != 2) {
        const float scale = (blockIdx.z == 0) ? QSCALE : 1.0f;
#pragma unroll
        for (int nt = 0; nt < 4; ++nt) {
            const int n_g = nb + ln0 + nt * 16 + lr;
            const float bb = bias[n_g];
            const int h = n_g >> 6, dh = n_g & 63;
#pragma unroll
            for (int mt = 0; mt < 4; ++mt)
#pragma unroll
                for (int r = 0; r < 4; ++r) {
                    const int m_g = mb + lm0 + mt * 16 + (lane >> 4) * 4 + r;
                    const int bi = m_g >> 11;
                    const int s  = m_g & (SEQ - 1);
                    dst[((size_t)((bi * NH + h) * SEQ + s)) * DH + dh] =
                        f2bf((acc[mt][nt][r] + bb) * scale);
                }
        }
    } else {
        // V: transpose via tbuf (aliases staging LDS; sync all waves first)
        __syncthreads();
        __bf16 (*tbuf)[64][72] = (__bf16 (*)[64][72])smem;
        const int h = (nb + ln0) >> 6;
#pragma unroll
        for (int nt = 0; nt < 4; ++nt) {
            const float bb = bias[nb + ln0 + nt * 16 + lr];
#pragma unroll
            for (int mt = 0; mt < 4; ++mt) {
                bf16x4 w;
#pragma unroll
                for (int r = 0; r < 4; ++r) w[r] = f2bf(acc[mt][nt][r] + bb);
                *(bf16x4*)&tbuf[wv][nt * 16 + lr][mt * 16 + (lane >> 4) * 4] = w;
            }
        }
#pragma unroll
        for (int i2 = 0; i2 < 8; ++i2) {
            const int row = i2 * 8 + (lane >> 3);
            const int sc_ = (lane & 7) * 8;
            bf16x8 val = *(const bf16x8*)&tbuf[wv][row][sc_];
            const int m_g = mb + lm0 + sc_;
            const int bi = m_g >> 11;
            const int s  = m_g & (SEQ - 1);
            *(bf16x8*)&dst[((size_t)((bi * NH + h) * DH + row)) * SEQ + s] = val;
        }
    }
}

// ---------------------------------------------------------------------------
// Unnormalized streaming attention with REGISTER P (R7) + l via ones-MFMA.
// K staged with row bit-permutation g(i)=[i5 i3 i2 i4 i1 i0] so exp2'd QK
// fragments are the PV A-fragments in-lane. l[q] = P x ones via MFMA, landing
// row-aligned with O (no shuffles anywhere in the main loop or epilogue).
// ---------------------------------------------------------------------------
__global__ __launch_bounds__(256) void attn_kernel(
    const __bf16* __restrict__ qh, const __bf16* __restrict__ kh,
    const __bf16* __restrict__ vT, float* __restrict__ out)
{
    __shared__ __align__(16) __bf16 kbuf[3][4096];   // 24 KB  [key][d] swizzled
    __shared__ __align__(16) __bf16 vbuf[3][4096];   // 24 KB  [d][key] swizzled

    const int tid  = threadIdx.x;
    const int lane = tid & 63;
    const int wv   = tid >> 6;
    const int i    = blockIdx.x;
    const int slot = i >> 3;
    const int bh   = (i & 7) * 4 + (slot >> 4);   // XCD x owns heads 4x..4x+3
    const int qt   = slot & 15;
    const size_t hb = (size_t)bh * SEQ * DH;
    const int q0 = qt * 128 + wv * 32;
    const int lq = lane & 15;
    const int lg = lane >> 4;
    const int swz = (lq & 7) << 4;

    // staging: chunk involution (pre-swizzled source), K rows bit-permuted g()
    const int p0 = tid, p1 = tid + 256;
    const int c0 = (p0 ^ ((p0 >> 3) & 7)) & 7;
    const int c1 = (p1 ^ ((p1 >> 3) & 7)) & 7;
    const int r0 = p0 >> 3, r1 = p1 >> 3;
    const int gr0 = (r0 & 35) | ((r0 & 12) << 1) | ((r0 & 16) >> 2);  // g(r0)
    const int gr1 = (r1 & 35) | ((r1 & 12) << 1) | ((r1 & 16) >> 2);  // g(r1)
    const __bf16* ks0 = kh + hb + (size_t)gr0 * DH + c0 * 8;
    const __bf16* ks1 = kh + hb + (size_t)gr1 * DH + c1 * 8;
    const __bf16* vs0 = vT + hb + (size_t)r0 * SEQ + c0 * 8;
    const __bf16* vs1 = vT + hb + (size_t)r1 * SEQ + c1 * 8;
    const int dst0 = wv * 512;
    const int dst1 = 2048 + wv * 512;

#define STAGE(SEL, TI) { \
    gload_lds16(ks0 + (size_t)(TI) * 64 * DH, &kbuf[SEL][dst0]); \
    gload_lds16(ks1 + (size_t)(TI) * 64 * DH, &kbuf[SEL][dst1]); \
    gload_lds16(vs0 + (TI) * 64, &vbuf[SEL][dst0]); \
    gload_lds16(vs1 + (TI) * 64, &vbuf[SEL][dst1]); }

    // Q fragments (pre-scaled by QSCALE at projection)
    bf16x8 bQ[2][2];
#pragma unroll
    for (int qtf = 0; qtf < 2; ++qtf)
#pragma unroll
        for (int ks = 0; ks < 2; ++ks)
            bQ[qtf][ks] = *(const bf16x8*)(qh + hb +
                (size_t)(q0 + qtf * 16 + lq) * DH + ks * 32 + lg * 8);

    bf16x8 ONES;
#pragma unroll
    for (int e = 0; e < 8; ++e) ONES[e] = f2bf(1.0f);

    f32x4 O[2][4];
#pragma unroll
    for (int qtf = 0; qtf < 2; ++qtf)
#pragma unroll
        for (int dt = 0; dt < 4; ++dt) O[qtf][dt] = (f32x4){0.f, 0.f, 0.f, 0.f};
    f32x4 Ol[2];   // l accumulator: Ol[qtf][r] = l for q-row lg*4+r (all cols equal)
    Ol[0] = (f32x4){0.f, 0.f, 0.f, 0.f};
    Ol[1] = (f32x4){0.f, 0.f, 0.f, 0.f};

    const int rdk0 = lq * 128 + ((0 * 64 + lg * 16) ^ swz);
    const int rdk1 = lq * 128 + ((1 * 64 + lg * 16) ^ swz);

    f32x4 scA[2][4], scB[2][4];
    bf16x8 paf[2][2];   // PV A-fragments [qtf][ks], built in-register

#define QK(SL, SC) { \
    const char* kc = (const char*)&kbuf[SL][0]; \
    _Pragma("unroll") for (int kt = 0; kt < 4; ++kt) { \
        const bf16x8 ak0 = *(const bf16x8*)(kc + kt * 2048 + rdk0); \
        const bf16x8 ak1 = *(const bf16x8*)(kc + kt * 2048 + rdk1); \
        _Pragma("unroll") for (int qtf = 0; qtf < 2; ++qtf) { \
            f32x4 c = (f32x4){0.f, 0.f, 0.f, 0.f}; \
            c = __builtin_amdgcn_mfma_f32_16x16x32_bf16(ak0, bQ[qtf][0], c, 0, 0, 0); \
            c = __builtin_amdgcn_mfma_f32_16x16x32_bf16(ak1, bQ[qtf][1], c, 0, 0, 0); \
            SC[qtf][kt] = c; } } }

    // unnormalized softmax: P = exp2(s) packed straight into PV A-fragments
#define SMAX(SC) { \
    _Pragma("unroll") for (int qtf = 0; qtf < 2; ++qtf) \
    _Pragma("unroll") for (int ks = 0; ks < 2; ++ks) { \
        bf16x8 w; \
        _Pragma("unroll") for (int r = 0; r < 4; ++r) { \
            w[r]     = f2bf(exp2f(SC[qtf][2 * ks][r])); \
            w[4 + r] = f2bf(exp2f(SC[qtf][2 * ks + 1][r])); } \
        paf[qtf][ks] = w; } }

#define PV(SL) { \
    const char* vc = (const char*)&vbuf[SL][0]; \
    _Pragma("unroll") for (int ks = 0; ks < 2; ++ks) { \
        const int rd = (ks == 0) ? rdk0 : rdk1; \
        _Pragma("unroll") for (int dt = 0; dt < 4; ++dt) { \
            const bf16x8 bv = *(const bf16x8*)(vc + dt * 2048 + rd); \
            O[0][dt] = __builtin_amdgcn_mfma_f32_16x16x32_bf16(paf[0][ks], bv, O[0][dt], 0, 0, 0); \
            O[1][dt] = __builtin_amdgcn_mfma_f32_16x16x32_bf16(paf[1][ks], bv, O[1][dt], 0, 0, 0); } \
        Ol[0] = __builtin_amdgcn_mfma_f32_16x16x32_bf16(paf[0][ks], ONES, Ol[0], 0, 0, 0); \
        Ol[1] = __builtin_amdgcn_mfma_f32_16x16x32_bf16(paf[1][ks], ONES, Ol[1], 0, 0, 0); } }

#define BODY(T, SCUR, SNXT) { \
    SMAX(SCUR); \
    __syncthreads(); \
    if ((T) + 2 < 32) STAGE(((T) + 2) % 3, (T) + 2); \
    __builtin_amdgcn_s_setprio(1); \
    if ((T) + 1 < 32) QK(((T) + 1) % 3, SNXT); \
    PV((T) % 3); \
    __builtin_amdgcn_s_setprio(0); }

    STAGE(0, 0);
    STAGE(1, 1);
    __syncthreads();
    QK(0, scA);

    for (int t = 0; t < 32; t += 2) {
        BODY(t, scA, scB);
        BODY(t + 1, scB, scA);
    }
#undef BODY
#undef PV
#undef SMAX
#undef QK
#undef STAGE

    // epilogue: Ol[qtf][r] is l for exactly the rows O[qtf][*][r] holds.
    const int b = bh >> 4, h = bh & 15;
#pragma unroll
    for (int qtf = 0; qtf < 2; ++qtf) {
#pragma unroll
        for (int r = 0; r < 4; ++r) {
            const float li = 1.0f / (qtf ? Ol[1][r] : Ol[0][r]);
            const int s_g = q0 + qtf * 16 + lg * 4 + r;
            float* op = out + ((size_t)(b * SEQ + s_g)) * DM + h * DH;
#pragma unroll
            for (int dt = 0; dt < 4; ++dt)
                op[dt * 16 + lq] = O[qtf][dt][r] * li;
        }
    }
}

// ---------------------------------------------------------------------------
extern "C" void kernel_launch(void* const* d_in, const int* in_sizes, int n_in,
                              void* d_out, int out_size, void* d_ws, size_t ws_size,
                              hipStream_t stream)
{
    (void)in_sizes; (void)n_in; (void)out_size; (void)ws_size;
    const float* q  = (const float*)d_in[0];
    const float* k  = (const float*)d_in[1];
    const float* v  = (const float*)d_in[2];
    const float* Wq = (const float*)d_in[3];
    const float* bq = (const float*)d_in[4];
    const float* Wk = (const float*)d_in[5];
    const float* bk = (const float*)d_in[6];
    const float* Wv = (const float*)d_in[7];
    const float* bv = (const float*)d_in[8];

    const size_t act = (size_t)ACT_N;
    __bf16* qhd = (__bf16*)d_ws;
    __bf16* khd = qhd + act;
    __bf16* vhd = khd + act;               // vhd: [bh][64][s] transposed
    float* out = (float*)d_out;

    proj3<<<dim3(32, 8, 3), dim3(256), 0, stream>>>(
        q, k, v, Wq, Wk, Wv, bq, bk, bv, qhd, khd, vhd);
    attn_kernel<<<dim3(512), dim3(256), 0, stream>>>(qhd, khd, vhd, out);
}

// Round 9
// 117.990 us; speedup vs baseline: 1.0817x; 1.0817x over previous
//
#include <hip/hip_runtime.h>
#include <stdint.h>
#include <stddef.h>

// MultiHeadAttention: B=2, S=2048, D=1024, H=16, Dh=64
// Round 9:
//   cvt6 : fp32->bf16 pre-convert (restored from R7 — fused fp32 staging in R8
//          doubled GEMM fetch+LDS bytes and regressed 2.5x; reverted)
//   proj3: bf16 NT GEMM, 128^2, global_load_lds (R7 verbatim)
//   attn : register-P unnormalized attention + l via ones-MFMA (R8) with
//          SMAX moved into the post-barrier region so its exp2/cvt VALU
//          interleaves under QK(t+1)'s MFMAs (serial softmax cost hidden).

#define NH  16
#define DH  64
#define SEQ 2048
#define DM  1024
#define NB  2

#define ACT_N (NB * SEQ * DM)   // 4194304
#define W_N   (DM * DM)         // 1048576
#define QSCALE 0.18033688011116012f   // log2(e)/sqrt(64)

typedef float  f32x4  __attribute__((ext_vector_type(4)));
typedef __bf16 bf16x8 __attribute__((ext_vector_type(8)));
typedef __bf16 bf16x4 __attribute__((ext_vector_type(4)));

__device__ __forceinline__ __bf16 f2bf(float f) { return (__bf16)f; }

__device__ __forceinline__ void gload_lds16(const void* g, void* l) {
    __builtin_amdgcn_global_load_lds(
        (const __attribute__((address_space(1))) void*)g,
        (__attribute__((address_space(3))) void*)l, 16, 0, 0);
}

// ---------------------------------------------------------------------------
__global__ __launch_bounds__(256) void cvt6(
    const float* __restrict__ s0, const float* __restrict__ s1,
    const float* __restrict__ s2, const float* __restrict__ s3,
    const float* __restrict__ s4, const float* __restrict__ s5,
    __bf16* __restrict__ d0, __bf16* __restrict__ d1, __bf16* __restrict__ d2,
    __bf16* __restrict__ d3, __bf16* __restrict__ d4, __bf16* __restrict__ d5)
{
    const float* s; __bf16* d; int n;
    switch (blockIdx.z) {
        case 0: s = s0; d = d0; n = ACT_N; break;
        case 1: s = s1; d = d1; n = ACT_N; break;
        case 2: s = s2; d = d2; n = ACT_N; break;
        case 3: s = s3; d = d3; n = W_N;   break;
        case 4: s = s4; d = d4; n = W_N;   break;
        default: s = s5; d = d5; n = W_N;  break;
    }
    const size_t i = ((size_t)blockIdx.x * 256 + threadIdx.x) * 8;
    if (i >= (size_t)n) return;
    float4 f0 = *(const float4*)(s + i);
    float4 f1 = *(const float4*)(s + i + 4);
    bf16x8 o;
    o[0] = f2bf(f0.x); o[1] = f2bf(f0.y); o[2] = f2bf(f0.z); o[3] = f2bf(f0.w);
    o[4] = f2bf(f1.x); o[5] = f2bf(f1.y); o[6] = f2bf(f1.z); o[7] = f2bf(f1.w);
    *(bf16x8*)(d + i) = o;
}

// ---------------------------------------------------------------------------
// proj3: NT GEMM, 128x128 tile, BK=32, global_load_lds staging (bf16).
// z==0: Q head-major, scaled; z==1: K head-major; z==2: V transposed [bh][64][s].
// ---------------------------------------------------------------------------
__global__ __launch_bounds__(256) void proj3(
    const __bf16* __restrict__ X0, const __bf16* __restrict__ X1, const __bf16* __restrict__ X2,
    const __bf16* __restrict__ W0, const __bf16* __restrict__ W1, const __bf16* __restrict__ W2,
    const float* __restrict__ b0, const float* __restrict__ b1, const float* __restrict__ b2,
    __bf16* __restrict__ dq, __bf16* __restrict__ dk, __bf16* __restrict__ dv)
{
    __shared__ __align__(16) __bf16 sA[128][32];
    __shared__ __align__(16) __bf16 sB[128][32];
    __shared__ __align__(16) __bf16 tbuf[4][64][72];

    const __bf16 *X, *W; const float* bias; __bf16* dst;
    if (blockIdx.z == 0)      { X = X0; W = W0; bias = b0; dst = dq; }
    else if (blockIdx.z == 1) { X = X1; W = W1; bias = b1; dst = dk; }
    else                      { X = X2; W = W2; bias = b2; dst = dv; }

    const int lane = threadIdx.x & 63;
    const int wv   = threadIdx.x >> 6;
    const int mb = blockIdx.x * 128;
    const int nb = blockIdx.y * 128;
    const int lm0 = (wv >> 1) * 64;
    const int ln0 = (wv & 1) * 64;
    const int lr = lane & 15;
    const int lk = (lane >> 4) * 8;
    const int srow = lane >> 2;
    const int scol = (lane & 3) * 8;

    f32x4 acc[4][4];
#pragma unroll
    for (int i = 0; i < 4; ++i)
#pragma unroll
        for (int j = 0; j < 4; ++j) acc[i][j] = (f32x4){0.f, 0.f, 0.f, 0.f};

    for (int k0 = 0; k0 < DM; k0 += 32) {
        __syncthreads();
#pragma unroll
        for (int c = wv * 2; c < wv * 2 + 2; ++c) {
            gload_lds16(X + (size_t)(mb + c * 16 + srow) * DM + k0 + scol, &sA[c * 16][0]);
            gload_lds16(W + (size_t)(nb + c * 16 + srow) * DM + k0 + scol, &sB[c * 16][0]);
        }
        __syncthreads();

        bf16x8 a[4], b[4];
#pragma unroll
        for (int t = 0; t < 4; ++t) {
            a[t] = *(const bf16x8*)&sA[lm0 + t * 16 + lr][lk];
            b[t] = *(const bf16x8*)&sB[ln0 + t * 16 + lr][lk];
        }
#pragma unroll
        for (int mt = 0; mt < 4; ++mt)
#pragma unroll
            for (int nt = 0; nt < 4; ++nt)
                acc[mt][nt] = __builtin_amdgcn_mfma_f32_16x16x32_bf16(
                    a[mt], b[nt], acc[mt][nt], 0, 0, 0);
    }

    if (blockIdx.z != 2) {
        const float scale = (blockIdx.z == 0) ? QSCALE : 1.0f;
#pragma unroll
        for (int nt = 0; nt < 4; ++nt) {
            const int n_g = nb + ln0 + nt * 16 + lr;
            const float bb = bias[n_g];
            const int h = n_g >> 6, dh = n_g & 63;
#pragma unroll
            for (int mt = 0; mt < 4; ++mt)
#pragma unroll
                for (int r = 0; r < 4; ++r) {
                    const int m_g = mb + lm0 + mt * 16 + (lane >> 4) * 4 + r;
                    const int bi = m_g >> 11;
                    const int s  = m_g & (SEQ - 1);
                    dst[((size_t)((bi * NH + h) * SEQ + s)) * DH + dh] =
                        f2bf((acc[mt][nt][r] + bb) * scale);
                }
        }
    } else {
        const int h = (nb + ln0) >> 6;
#pragma unroll
        for (int nt = 0; nt < 4; ++nt) {
            const float bb = bias[nb + ln0 + nt * 16 + lr];
#pragma unroll
            for (int mt = 0; mt < 4; ++mt) {
                bf16x4 w;
#pragma unroll
                for (int r = 0; r < 4; ++r) w[r] = f2bf(acc[mt][nt][r] + bb);
                *(bf16x4*)&tbuf[wv][nt * 16 + lr][mt * 16 + (lane >> 4) * 4] = w;
            }
        }
#pragma unroll
        for (int i2 = 0; i2 < 8; ++i2) {
            const int row = i2 * 8 + (lane >> 3);
            const int sc_ = (lane & 7) * 8;
            bf16x8 val = *(const bf16x8*)&tbuf[wv][row][sc_];
            const int m_g = mb + lm0 + sc_;
            const int bi = m_g >> 11;
            const int s  = m_g & (SEQ - 1);
            *(bf16x8*)&dst[((size_t)((bi * NH + h) * DH + row)) * SEQ + s] = val;
        }
    }
}

// ---------------------------------------------------------------------------
// Unnormalized streaming attention, register P, l via ones-MFMA.
// Per iter: barrier | STAGE(t+2) ; QK(t+1) ∥ SMAX(t) ; PV(t).
// SMAX VALU/exp2 interleaves under QK's MFMAs (separate pipes).
// ---------------------------------------------------------------------------
__global__ __launch_bounds__(256) void attn_kernel(
    const __bf16* __restrict__ qh, const __bf16* __restrict__ kh,
    const __bf16* __restrict__ vT, float* __restrict__ out)
{
    __shared__ __align__(16) __bf16 kbuf[3][4096];   // 24 KB  [key][d] swizzled
    __shared__ __align__(16) __bf16 vbuf[3][4096];   // 24 KB  [d][key] swizzled

    const int tid  = threadIdx.x;
    const int lane = tid & 63;
    const int wv   = tid >> 6;
    const int i    = blockIdx.x;
    const int slot = i >> 3;
    const int bh   = (i & 7) * 4 + (slot >> 4);   // XCD x owns heads 4x..4x+3
    const int qt   = slot & 15;
    const size_t hb = (size_t)bh * SEQ * DH;
    const int q0 = qt * 128 + wv * 32;
    const int lq = lane & 15;
    const int lg = lane >> 4;
    const int swz = (lq & 7) << 4;

    // staging: chunk involution (pre-swizzled source), K rows bit-permuted g()
    const int p0 = tid, p1 = tid + 256;
    const int c0 = (p0 ^ ((p0 >> 3) & 7)) & 7;
    const int c1 = (p1 ^ ((p1 >> 3) & 7)) & 7;
    const int r0 = p0 >> 3, r1 = p1 >> 3;
    const int gr0 = (r0 & 35) | ((r0 & 12) << 1) | ((r0 & 16) >> 2);  // g(r0)
    const int gr1 = (r1 & 35) | ((r1 & 12) << 1) | ((r1 & 16) >> 2);  // g(r1)
    const __bf16* ks0 = kh + hb + (size_t)gr0 * DH + c0 * 8;
    const __bf16* ks1 = kh + hb + (size_t)gr1 * DH + c1 * 8;
    const __bf16* vs0 = vT + hb + (size_t)r0 * SEQ + c0 * 8;
    const __bf16* vs1 = vT + hb + (size_t)r1 * SEQ + c1 * 8;
    const int dst0 = wv * 512;
    const int dst1 = 2048 + wv * 512;

#define STAGE(SEL, TI) { \
    gload_lds16(ks0 + (size_t)(TI) * 64 * DH, &kbuf[SEL][dst0]); \
    gload_lds16(ks1 + (size_t)(TI) * 64 * DH, &kbuf[SEL][dst1]); \
    gload_lds16(vs0 + (TI) * 64, &vbuf[SEL][dst0]); \
    gload_lds16(vs1 + (TI) * 64, &vbuf[SEL][dst1]); }

    // Q fragments (pre-scaled by QSCALE at projection)
    bf16x8 bQ[2][2];
#pragma unroll
    for (int qtf = 0; qtf < 2; ++qtf)
#pragma unroll
        for (int ks = 0; ks < 2; ++ks)
            bQ[qtf][ks] = *(const bf16x8*)(qh + hb +
                (size_t)(q0 + qtf * 16 + lq) * DH + ks * 32 + lg * 8);

    bf16x8 ONES;
#pragma unroll
    for (int e = 0; e < 8; ++e) ONES[e] = f2bf(1.0f);

    f32x4 O[2][4];
#pragma unroll
    for (int qtf = 0; qtf < 2; ++qtf)
#pragma unroll
        for (int dt = 0; dt < 4; ++dt) O[qtf][dt] = (f32x4){0.f, 0.f, 0.f, 0.f};
    f32x4 Ol[2];
    Ol[0] = (f32x4){0.f, 0.f, 0.f, 0.f};
    Ol[1] = (f32x4){0.f, 0.f, 0.f, 0.f};

    const int rdk0 = lq * 128 + ((0 * 64 + lg * 16) ^ swz);
    const int rdk1 = lq * 128 + ((1 * 64 + lg * 16) ^ swz);

    f32x4 scA[2][4], scB[2][4];
    bf16x8 paf[2][2];   // PV A-fragments [qtf][ks], built in-register

#define QK(SL, SC) { \
    const char* kc = (const char*)&kbuf[SL][0]; \
    _Pragma("unroll") for (int kt = 0; kt < 4; ++kt) { \
        const bf16x8 ak0 = *(const bf16x8*)(kc + kt * 2048 + rdk0); \
        const bf16x8 ak1 = *(const bf16x8*)(kc + kt * 2048 + rdk1); \
        _Pragma("unroll") for (int qtf = 0; qtf < 2; ++qtf) { \
            f32x4 c = (f32x4){0.f, 0.f, 0.f, 0.f}; \
            c = __builtin_amdgcn_mfma_f32_16x16x32_bf16(ak0, bQ[qtf][0], c, 0, 0, 0); \
            c = __builtin_amdgcn_mfma_f32_16x16x32_bf16(ak1, bQ[qtf][1], c, 0, 0, 0); \
            SC[qtf][kt] = c; } } }

    // unnormalized softmax: P = exp2(s) packed straight into PV A-fragments
#define SMAX(SC) { \
    _Pragma("unroll") for (int qtf = 0; qtf < 2; ++qtf) \
    _Pragma("unroll") for (int ks = 0; ks < 2; ++ks) { \
        bf16x8 w; \
        _Pragma("unroll") for (int r = 0; r < 4; ++r) { \
            w[r]     = f2bf(exp2f(SC[qtf][2 * ks][r])); \
            w[4 + r] = f2bf(exp2f(SC[qtf][2 * ks + 1][r])); } \
        paf[qtf][ks] = w; } }

#define PV(SL) { \
    const char* vc = (const char*)&vbuf[SL][0]; \
    _Pragma("unroll") for (int ks = 0; ks < 2; ++ks) { \
        const int rd = (ks == 0) ? rdk0 : rdk1; \
        _Pragma("unroll") for (int dt = 0; dt < 4; ++dt) { \
            const bf16x8 bv = *(const bf16x8*)(vc + dt * 2048 + rd); \
            O[0][dt] = __builtin_amdgcn_mfma_f32_16x16x32_bf16(paf[0][ks], bv, O[0][dt], 0, 0, 0); \
            O[1][dt] = __builtin_amdgcn_mfma_f32_16x16x32_bf16(paf[1][ks], bv, O[1][dt], 0, 0, 0); } \
        Ol[0] = __builtin_amdgcn_mfma_f32_16x16x32_bf16(paf[0][ks], ONES, Ol[0], 0, 0, 0); \
        Ol[1] = __builtin_amdgcn_mfma_f32_16x16x32_bf16(paf[1][ks], ONES, Ol[1], 0, 0, 0); } }

// barrier first; then STAGE(t+2) + QK(t+1) (independent) interleave with
// SMAX(t)'s exp2/cvt; PV(t) consumes paf. One barrier/tile.
#define BODY(T, SCUR, SNXT) { \
    __syncthreads(); \
    if ((T) + 2 < 32) STAGE(((T) + 2) % 3, (T) + 2); \
    __builtin_amdgcn_s_setprio(1); \
    if ((T) + 1 < 32) QK(((T) + 1) % 3, SNXT); \
    SMAX(SCUR); \
    PV((T) % 3); \
    __builtin_amdgcn_s_setprio(0); }

    STAGE(0, 0);
    STAGE(1, 1);
    __syncthreads();
    QK(0, scA);

    for (int t = 0; t < 32; t += 2) {
        BODY(t, scA, scB);
        BODY(t + 1, scB, scA);
    }
#undef BODY
#undef PV
#undef SMAX
#undef QK
#undef STAGE

    // epilogue: Ol[qtf][r] is l for exactly the rows O[qtf][*][r] holds.
    const int b = bh >> 4, h = bh & 15;
#pragma unroll
    for (int qtf = 0; qtf < 2; ++qtf) {
#pragma unroll
        for (int r = 0; r < 4; ++r) {
            const float li = 1.0f / (qtf ? Ol[1][r] : Ol[0][r]);
            const int s_g = q0 + qtf * 16 + lg * 4 + r;
            float* op = out + ((size_t)(b * SEQ + s_g)) * DM + h * DH;
#pragma unroll
            for (int dt = 0; dt < 4; ++dt)
                op[dt * 16 + lq] = O[qtf][dt][r] * li;
        }
    }
}

// ---------------------------------------------------------------------------
extern "C" void kernel_launch(void* const* d_in, const int* in_sizes, int n_in,
                              void* d_out, int out_size, void* d_ws, size_t ws_size,
                              hipStream_t stream)
{
    (void)in_sizes; (void)n_in; (void)out_size; (void)ws_size;
    const float* q  = (const float*)d_in[0];
    const float* k  = (const float*)d_in[1];
    const float* v  = (const float*)d_in[2];
    const float* Wq = (const float*)d_in[3];
    const float* bq = (const float*)d_in[4];
    const float* Wk = (const float*)d_in[5];
    const float* bk = (const float*)d_in[6];
    const float* Wv = (const float*)d_in[7];
    const float* bv = (const float*)d_in[8];

    const size_t act = (size_t)ACT_N;
    const size_t wn  = (size_t)W_N;
    __bf16* qx  = (__bf16*)d_ws;
    __bf16* kx  = qx + act;
    __bf16* vx  = kx + act;
    __bf16* wqb = vx + act;
    __bf16* wkb = wqb + wn;
    __bf16* wvb = wkb + wn;
    __bf16* qhd = wvb + wn;
    __bf16* khd = qhd + act;
    __bf16* vhd = khd + act;               // vhd: [bh][64][s] transposed
    float* out = (float*)d_out;

    cvt6<<<dim3(2048, 1, 6), dim3(256), 0, stream>>>(
        q, k, v, Wq, Wk, Wv, qx, kx, vx, wqb, wkb, wvb);
    proj3<<<dim3(32, 8, 3), dim3(256), 0, stream>>>(
        qx, kx, vx, wqb, wkb, wvb, bq, bk, bv, qhd, khd, vhd);
    attn_kernel<<<dim3(512), dim3(256), 0, stream>>>(qhd, khd, vhd, out);
}

// Round 10
// 99.442 us; speedup vs baseline: 1.2834x; 1.1865x over previous
//
#include <hip/hip_runtime.h>
#include <stdint.h>
#include <stddef.h>

// MultiHeadAttention: B=2, S=2048, D=1024, H=16, Dh=64
// Round 10:
//   cvt6 : fp32->bf16 pre-convert (unchanged)
//   proj3: bf16 NT GEMM 128^2 (unchanged)
//   attn : register-P unnormalized attention, l via ones-MFMA, with
//          (1) FULLY UNROLLED tile loop (slot indices / LDS offsets / guards
//              all compile-time; no mod-3, ds_read base+imm),
//          (2) raw v_exp_f32 (skips ocml fixups; input bounded),
//          (3) SMAX before the barrier (R7 order, measured better than R9).

#define NH  16
#define DH  64
#define SEQ 2048
#define DM  1024
#define NB  2

#define ACT_N (NB * SEQ * DM)   // 4194304
#define W_N   (DM * DM)         // 1048576
#define QSCALE 0.18033688011116012f   // log2(e)/sqrt(64)

typedef float  f32x4  __attribute__((ext_vector_type(4)));
typedef __bf16 bf16x8 __attribute__((ext_vector_type(8)));
typedef __bf16 bf16x4 __attribute__((ext_vector_type(4)));

__device__ __forceinline__ __bf16 f2bf(float f) { return (__bf16)f; }

__device__ __forceinline__ float fexp2(float x) {
    float r; asm("v_exp_f32 %0, %1" : "=v"(r) : "v"(x)); return r;
}

__device__ __forceinline__ void gload_lds16(const void* g, void* l) {
    __builtin_amdgcn_global_load_lds(
        (const __attribute__((address_space(1))) void*)g,
        (__attribute__((address_space(3))) void*)l, 16, 0, 0);
}

// ---------------------------------------------------------------------------
__global__ __launch_bounds__(256) void cvt6(
    const float* __restrict__ s0, const float* __restrict__ s1,
    const float* __restrict__ s2, const float* __restrict__ s3,
    const float* __restrict__ s4, const float* __restrict__ s5,
    __bf16* __restrict__ d0, __bf16* __restrict__ d1, __bf16* __restrict__ d2,
    __bf16* __restrict__ d3, __bf16* __restrict__ d4, __bf16* __restrict__ d5)
{
    const float* s; __bf16* d; int n;
    switch (blockIdx.z) {
        case 0: s = s0; d = d0; n = ACT_N; break;
        case 1: s = s1; d = d1; n = ACT_N; break;
        case 2: s = s2; d = d2; n = ACT_N; break;
        case 3: s = s3; d = d3; n = W_N;   break;
        case 4: s = s4; d = d4; n = W_N;   break;
        default: s = s5; d = d5; n = W_N;  break;
    }
    const size_t i = ((size_t)blockIdx.x * 256 + threadIdx.x) * 8;
    if (i >= (size_t)n) return;
    float4 f0 = *(const float4*)(s + i);
    float4 f1 = *(const float4*)(s + i + 4);
    bf16x8 o;
    o[0] = f2bf(f0.x); o[1] = f2bf(f0.y); o[2] = f2bf(f0.z); o[3] = f2bf(f0.w);
    o[4] = f2bf(f1.x); o[5] = f2bf(f1.y); o[6] = f2bf(f1.z); o[7] = f2bf(f1.w);
    *(bf16x8*)(d + i) = o;
}

// ---------------------------------------------------------------------------
// proj3: NT GEMM, 128x128 tile, BK=32, global_load_lds staging (bf16).
// z==0: Q head-major, scaled; z==1: K head-major; z==2: V transposed [bh][64][s].
// ---------------------------------------------------------------------------
__global__ __launch_bounds__(256) void proj3(
    const __bf16* __restrict__ X0, const __bf16* __restrict__ X1, const __bf16* __restrict__ X2,
    const __bf16* __restrict__ W0, const __bf16* __restrict__ W1, const __bf16* __restrict__ W2,
    const float* __restrict__ b0, const float* __restrict__ b1, const float* __restrict__ b2,
    __bf16* __restrict__ dq, __bf16* __restrict__ dk, __bf16* __restrict__ dv)
{
    __shared__ __align__(16) __bf16 sA[128][32];
    __shared__ __align__(16) __bf16 sB[128][32];
    __shared__ __align__(16) __bf16 tbuf[4][64][72];

    const __bf16 *X, *W; const float* bias; __bf16* dst;
    if (blockIdx.z == 0)      { X = X0; W = W0; bias = b0; dst = dq; }
    else if (blockIdx.z == 1) { X = X1; W = W1; bias = b1; dst = dk; }
    else                      { X = X2; W = W2; bias = b2; dst = dv; }

    const int lane = threadIdx.x & 63;
    const int wv   = threadIdx.x >> 6;
    const int mb = blockIdx.x * 128;
    const int nb = blockIdx.y * 128;
    const int lm0 = (wv >> 1) * 64;
    const int ln0 = (wv & 1) * 64;
    const int lr = lane & 15;
    const int lk = (lane >> 4) * 8;
    const int srow = lane >> 2;
    const int scol = (lane & 3) * 8;

    f32x4 acc[4][4];
#pragma unroll
    for (int i = 0; i < 4; ++i)
#pragma unroll
        for (int j = 0; j < 4; ++j) acc[i][j] = (f32x4){0.f, 0.f, 0.f, 0.f};

    for (int k0 = 0; k0 < DM; k0 += 32) {
        __syncthreads();
#pragma unroll
        for (int c = wv * 2; c < wv * 2 + 2; ++c) {
            gload_lds16(X + (size_t)(mb + c * 16 + srow) * DM + k0 + scol, &sA[c * 16][0]);
            gload_lds16(W + (size_t)(nb + c * 16 + srow) * DM + k0 + scol, &sB[c * 16][0]);
        }
        __syncthreads();

        bf16x8 a[4], b[4];
#pragma unroll
        for (int t = 0; t < 4; ++t) {
            a[t] = *(const bf16x8*)&sA[lm0 + t * 16 + lr][lk];
            b[t] = *(const bf16x8*)&sB[ln0 + t * 16 + lr][lk];
        }
#pragma unroll
        for (int mt = 0; mt < 4; ++mt)
#pragma unroll
            for (int nt = 0; nt < 4; ++nt)
                acc[mt][nt] = __builtin_amdgcn_mfma_f32_16x16x32_bf16(
                    a[mt], b[nt], acc[mt][nt], 0, 0, 0);
    }

    if (blockIdx.z != 2) {
        const float scale = (blockIdx.z == 0) ? QSCALE : 1.0f;
#pragma unroll
        for (int nt = 0; nt < 4; ++nt) {
            const int n_g = nb + ln0 + nt * 16 + lr;
            const float bb = bias[n_g];
            const int h = n_g >> 6, dh = n_g & 63;
#pragma unroll
            for (int mt = 0; mt < 4; ++mt)
#pragma unroll
                for (int r = 0; r < 4; ++r) {
                    const int m_g = mb + lm0 + mt * 16 + (lane >> 4) * 4 + r;
                    const int bi = m_g >> 11;
                    const int s  = m_g & (SEQ - 1);
                    dst[((size_t)((bi * NH + h) * SEQ + s)) * DH + dh] =
                        f2bf((acc[mt][nt][r] + bb) * scale);
                }
        }
    } else {
        const int h = (nb + ln0) >> 6;
#pragma unroll
        for (int nt = 0; nt < 4; ++nt) {
            const float bb = bias[nb + ln0 + nt * 16 + lr];
#pragma unroll
            for (int mt = 0; mt < 4; ++mt) {
                bf16x4 w;
#pragma unroll
                for (int r = 0; r < 4; ++r) w[r] = f2bf(acc[mt][nt][r] + bb);
                *(bf16x4*)&tbuf[wv][nt * 16 + lr][mt * 16 + (lane >> 4) * 4] = w;
            }
        }
#pragma unroll
        for (int i2 = 0; i2 < 8; ++i2) {
            const int row = i2 * 8 + (lane >> 3);
            const int sc_ = (lane & 7) * 8;
            bf16x8 val = *(const bf16x8*)&tbuf[wv][row][sc_];
            const int m_g = mb + lm0 + sc_;
            const int bi = m_g >> 11;
            const int s  = m_g & (SEQ - 1);
            *(bf16x8*)&dst[((size_t)((bi * NH + h) * DH + row)) * SEQ + s] = val;
        }
    }
}

// ---------------------------------------------------------------------------
// Unnormalized streaming attention, register P, l via ones-MFMA, FULL UNROLL.
// Per tile: SMAX(t) | barrier | STAGE(t+2) ; QK(t+1) ; PV(t).
// ---------------------------------------------------------------------------
__global__ __launch_bounds__(256) void attn_kernel(
    const __bf16* __restrict__ qh, const __bf16* __restrict__ kh,
    const __bf16* __restrict__ vT, float* __restrict__ out)
{
    __shared__ __align__(16) __bf16 kbuf[3][4096];   // 24 KB  [key][d] swizzled
    __shared__ __align__(16) __bf16 vbuf[3][4096];   // 24 KB  [d][key] swizzled

    const int tid  = threadIdx.x;
    const int lane = tid & 63;
    const int wv   = tid >> 6;
    const int i    = blockIdx.x;
    const int slot = i >> 3;
    const int bh   = (i & 7) * 4 + (slot >> 4);   // XCD x owns heads 4x..4x+3
    const int qt   = slot & 15;
    const size_t hb = (size_t)bh * SEQ * DH;
    const int q0 = qt * 128 + wv * 32;
    const int lq = lane & 15;
    const int lg = lane >> 4;
    const int swz = (lq & 7) << 4;

    // staging: chunk involution (pre-swizzled source), K rows bit-permuted g()
    const int p0 = tid, p1 = tid + 256;
    const int c0 = (p0 ^ ((p0 >> 3) & 7)) & 7;
    const int c1 = (p1 ^ ((p1 >> 3) & 7)) & 7;
    const int r0 = p0 >> 3, r1 = p1 >> 3;
    const int gr0 = (r0 & 35) | ((r0 & 12) << 1) | ((r0 & 16) >> 2);  // g(r0)
    const int gr1 = (r1 & 35) | ((r1 & 12) << 1) | ((r1 & 16) >> 2);  // g(r1)
    const __bf16* ks0 = kh + hb + (size_t)gr0 * DH + c0 * 8;
    const __bf16* ks1 = kh + hb + (size_t)gr1 * DH + c1 * 8;
    const __bf16* vs0 = vT + hb + (size_t)r0 * SEQ + c0 * 8;
    const __bf16* vs1 = vT + hb + (size_t)r1 * SEQ + c1 * 8;
    const int dst0 = wv * 512;
    const int dst1 = 2048 + wv * 512;

#define STAGE(SEL, TI) { \
    gload_lds16(ks0 + (size_t)(TI) * 64 * DH, &kbuf[SEL][dst0]); \
    gload_lds16(ks1 + (size_t)(TI) * 64 * DH, &kbuf[SEL][dst1]); \
    gload_lds16(vs0 + (TI) * 64, &vbuf[SEL][dst0]); \
    gload_lds16(vs1 + (TI) * 64, &vbuf[SEL][dst1]); }

    // Q fragments (pre-scaled by QSCALE at projection)
    bf16x8 bQ[2][2];
#pragma unroll
    for (int qtf = 0; qtf < 2; ++qtf)
#pragma unroll
        for (int ks = 0; ks < 2; ++ks)
            bQ[qtf][ks] = *(const bf16x8*)(qh + hb +
                (size_t)(q0 + qtf * 16 + lq) * DH + ks * 32 + lg * 8);

    bf16x8 ONES;
#pragma unroll
    for (int e = 0; e < 8; ++e) ONES[e] = f2bf(1.0f);

    f32x4 O[2][4];
#pragma unroll
    for (int qtf = 0; qtf < 2; ++qtf)
#pragma unroll
        for (int dt = 0; dt < 4; ++dt) O[qtf][dt] = (f32x4){0.f, 0.f, 0.f, 0.f};
    f32x4 Ol[2];
    Ol[0] = (f32x4){0.f, 0.f, 0.f, 0.f};
    Ol[1] = (f32x4){0.f, 0.f, 0.f, 0.f};

    const int rdk0 = lq * 128 + ((0 * 64 + lg * 16) ^ swz);
    const int rdk1 = lq * 128 + ((1 * 64 + lg * 16) ^ swz);

    f32x4 scA[2][4], scB[2][4];
    bf16x8 paf[2][2];   // PV A-fragments [qtf][ks], built in-register

#define QK(SL, SC) { \
    const char* kc = (const char*)&kbuf[SL][0]; \
    _Pragma("unroll") for (int kt = 0; kt < 4; ++kt) { \
        const bf16x8 ak0 = *(const bf16x8*)(kc + kt * 2048 + rdk0); \
        const bf16x8 ak1 = *(const bf16x8*)(kc + kt * 2048 + rdk1); \
        _Pragma("unroll") for (int qtf = 0; qtf < 2; ++qtf) { \
            f32x4 c = (f32x4){0.f, 0.f, 0.f, 0.f}; \
            c = __builtin_amdgcn_mfma_f32_16x16x32_bf16(ak0, bQ[qtf][0], c, 0, 0, 0); \
            c = __builtin_amdgcn_mfma_f32_16x16x32_bf16(ak1, bQ[qtf][1], c, 0, 0, 0); \
            SC[qtf][kt] = c; } } }

    // unnormalized softmax: P = exp2(s) packed straight into PV A-fragments
#define SMAX(SC) { \
    _Pragma("unroll") for (int qtf = 0; qtf < 2; ++qtf) \
    _Pragma("unroll") for (int ks = 0; ks < 2; ++ks) { \
        bf16x8 w; \
        _Pragma("unroll") for (int r = 0; r < 4; ++r) { \
            w[r]     = f2bf(fexp2(SC[qtf][2 * ks][r])); \
            w[4 + r] = f2bf(fexp2(SC[qtf][2 * ks + 1][r])); } \
        paf[qtf][ks] = w; } }

#define PV(SL) { \
    const char* vc = (const char*)&vbuf[SL][0]; \
    _Pragma("unroll") for (int ks = 0; ks < 2; ++ks) { \
        const int rd = (ks == 0) ? rdk0 : rdk1; \
        _Pragma("unroll") for (int dt = 0; dt < 4; ++dt) { \
            const bf16x8 bv = *(const bf16x8*)(vc + dt * 2048 + rd); \
            O[0][dt] = __builtin_amdgcn_mfma_f32_16x16x32_bf16(paf[0][ks], bv, O[0][dt], 0, 0, 0); \
            O[1][dt] = __builtin_amdgcn_mfma_f32_16x16x32_bf16(paf[1][ks], bv, O[1][dt], 0, 0, 0); } \
        Ol[0] = __builtin_amdgcn_mfma_f32_16x16x32_bf16(paf[0][ks], ONES, Ol[0], 0, 0, 0); \
        Ol[1] = __builtin_amdgcn_mfma_f32_16x16x32_bf16(paf[1][ks], ONES, Ol[1], 0, 0, 0); } }

// R7 order: SMAX(t) before barrier (sc from previous region; paf is register).
#define BODY(T, SCUR, SNXT) { \
    SMAX(SCUR); \
    __syncthreads(); \
    if ((T) + 2 < 32) STAGE(((T) + 2) % 3, (T) + 2); \
    __builtin_amdgcn_s_setprio(1); \
    if ((T) + 1 < 32) QK(((T) + 1) % 3, SNXT); \
    PV((T) % 3); \
    __builtin_amdgcn_s_setprio(0); }

    STAGE(0, 0);
    STAGE(1, 1);
    __syncthreads();
    QK(0, scA);

#pragma unroll
    for (int t = 0; t < 32; t += 2) {   // FULL unroll: T, slots, offsets constant
        BODY(t, scA, scB);
        BODY(t + 1, scB, scA);
    }
#undef BODY
#undef PV
#undef SMAX
#undef QK
#undef STAGE

    // epilogue: Ol[qtf][r] is l for exactly the rows O[qtf][*][r] holds.
    const int b = bh >> 4, h = bh & 15;
#pragma unroll
    for (int qtf = 0; qtf < 2; ++qtf) {
#pragma unroll
        for (int r = 0; r < 4; ++r) {
            const float li = 1.0f / (qtf ? Ol[1][r] : Ol[0][r]);
            const int s_g = q0 + qtf * 16 + lg * 4 + r;
            float* op = out + ((size_t)(b * SEQ + s_g)) * DM + h * DH;
#pragma unroll
            for (int dt = 0; dt < 4; ++dt)
                op[dt * 16 + lq] = O[qtf][dt][r] * li;
        }
    }
}

// ---------------------------------------------------------------------------
extern "C" void kernel_launch(void* const* d_in, const int* in_sizes, int n_in,
                              void* d_out, int out_size, void* d_ws, size_t ws_size,
                              hipStream_t stream)
{
    (void)in_sizes; (void)n_in; (void)out_size; (void)ws_size;
    const float* q  = (const float*)d_in[0];
    const float* k  = (const float*)d_in[1];
    const float* v  = (const float*)d_in[2];
    const float* Wq = (const float*)d_in[3];
    const float* bq = (const float*)d_in[4];
    const float* Wk = (const float*)d_in[5];
    const float* bk = (const float*)d_in[6];
    const float* Wv = (const float*)d_in[7];
    const float* bv = (const float*)d_in[8];

    const size_t act = (size_t)ACT_N;
    const size_t wn  = (size_t)W_N;
    __bf16* qx  = (__bf16*)d_ws;
    __bf16* kx  = qx + act;
    __bf16* vx  = kx + act;
    __bf16* wqb = vx + act;
    __bf16* wkb = wqb + wn;
    __bf16* wvb = wkb + wn;
    __bf16* qhd = wvb + wn;
    __bf16* khd = qhd + act;
    __bf16* vhd = khd + act;               // vhd: [bh][64][s] transposed
    float* out = (float*)d_out;

    cvt6<<<dim3(2048, 1, 6), dim3(256), 0, stream>>>(
        q, k, v, Wq, Wk, Wv, qx, kx, vx, wqb, wkb, wvb);
    proj3<<<dim3(32, 8, 3), dim3(256), 0, stream>>>(
        qx, kx, vx, wqb, wkb, wvb, bq, bk, bv, qhd, khd, vhd);
    attn_kernel<<<dim3(512), dim3(256), 0, stream>>>(qhd, khd, vhd, out);
}